// Round 7
// baseline (222.120 us; speedup 1.0000x reference)
//
#include <hip/hip_runtime.h>
#include <stdint.h>

// LIF recurrence: mem = tau*mem + x[t]; spike = (mem > v_th); mem *= (1-spike)
// x [T,B,C,H,W] fp32, mem0 [1,C,H,W] fp32, out [T,B,C,H,W] fp32.
// T=4, B=64, C=128, H=W=32. n4 = 2^21 float4 per timestep.
//
// Falsification ledger (kernel time = harness dur - ~147us fixed overhead):
//   R0: serialized loads                           84us (VGPR=16, full occ)
//   R1: sunk array hoist + builtin nt-store       104us (confounded: grid/2)
//   R2: forced 10-deep MLP (sched_barrier)        ~81us -> MLP null
//   R3: t-plane sweep, a/b ping-pong prefetch     ~81us -> stream-count null
//   R4: asm `sc1 nt` stores                        FAIL -> scope-bypass banned
//   R5: + builtin NT LOADS on x                   ~75us -> WIN (+8%)
//   R6: + builtin NT STORES on out                ~72.5us -> WIN (+3%)
// Remaining uncontrolled variable: OCCUPANCY. The IPT=4 straight-line
// skeleton holds ~14 live float4 (~>64 VGPR) -> likely 6 waves/SIMD, a
// 25% concurrency cut none of the probes controlled (R0 proved VGPR=16/full
// occ possible, but had no nt). R7 = nt-skeleton at forced full occupancy:
// IPT=2 (live set ~30 VGPR) + __launch_bounds__(256,8) pins <=64 VGPR.
// Predict: VGPR<=64, occupancy 69->85+, kernel 72.5 -> 60-65us if occupancy
// was the limiter; if null, ledger complete -> structural ceiling.

#ifndef LIF_T
#define LIF_T 4
#endif

#define BLOCK 256
#define IPT 2   // block-contiguous float4 per thread: 8KB/block per t-plane

typedef float vfloat4 __attribute__((ext_vector_type(4)));

__device__ __forceinline__ float4 load_nt(const float4* p) {
    vfloat4 v = __builtin_nontemporal_load((const vfloat4*)p);
    return make_float4(v.x, v.y, v.z, v.w);
}

__device__ __forceinline__ void store_nt(float4* p, float4 v) {
    vfloat4 d = {v.x, v.y, v.z, v.w};
    __builtin_nontemporal_store(d, (vfloat4*)p);
}

__device__ __forceinline__ float4 lif_step(float4& mem, const float4 xt) {
    const float TAU = 0.25f;
    const float V_TH = 1.0f;
    float4 s;
    mem.x = TAU * mem.x + xt.x;
    mem.y = TAU * mem.y + xt.y;
    mem.z = TAU * mem.z + xt.z;
    mem.w = TAU * mem.w + xt.w;
    s.x = (mem.x > V_TH) ? 1.0f : 0.0f;
    s.y = (mem.y > V_TH) ? 1.0f : 0.0f;
    s.z = (mem.z > V_TH) ? 1.0f : 0.0f;
    s.w = (mem.w > V_TH) ? 1.0f : 0.0f;
    mem.x = (mem.x > V_TH) ? 0.0f : mem.x;
    mem.y = (mem.y > V_TH) ? 0.0f : mem.y;
    mem.z = (mem.z > V_TH) ? 0.0f : mem.z;
    mem.w = (mem.w > V_TH) ? 0.0f : mem.w;
    return s;
}

__global__ __launch_bounds__(BLOCK, 8) void
lif_kernel(const float4* __restrict__ x,     // [T, N4] float4 view
           const float4* __restrict__ mem0,  // [CHW4] float4 view (broadcast over B)
           float4* __restrict__ out,         // [T, N4]
           int n4, int chw4_mask) {
    const int base = blockIdx.x * (BLOCK * IPT) + threadIdx.x;
    const int i0 = base;
    const int i1 = base + BLOCK;

    if (i1 < n4) {
        float4 m0 = mem0[i0 & chw4_mask];
        float4 m1 = mem0[i1 & chw4_mask];

        // t=0 plane loads (a-set), non-temporal (x is dead-on-read).
        float4 a0 = load_nt(&x[i0]), a1 = load_nt(&x[i1]);
        float4 b0, b1;

        // ---- t=0: compute on a, prefetch t=1 into b, nt-store ----
        a0 = lif_step(m0, a0); a1 = lif_step(m1, a1);
        b0 = load_nt(&x[n4 + i0]); b1 = load_nt(&x[n4 + i1]);
        __builtin_amdgcn_sched_barrier(0);   // keep prefetch above the stores
        store_nt(&out[i0], a0); store_nt(&out[i1], a1);

        // ---- t=1 ----
        b0 = lif_step(m0, b0); b1 = lif_step(m1, b1);
        a0 = load_nt(&x[2 * n4 + i0]); a1 = load_nt(&x[2 * n4 + i1]);
        __builtin_amdgcn_sched_barrier(0);
        store_nt(&out[n4 + i0], b0); store_nt(&out[n4 + i1], b1);

        // ---- t=2 ----
        a0 = lif_step(m0, a0); a1 = lif_step(m1, a1);
        b0 = load_nt(&x[3 * n4 + i0]); b1 = load_nt(&x[3 * n4 + i1]);
        __builtin_amdgcn_sched_barrier(0);
        store_nt(&out[2 * n4 + i0], a0); store_nt(&out[2 * n4 + i1], a1);

        // ---- t=3 ----
        b0 = lif_step(m0, b0); b1 = lif_step(m1, b1);
        store_nt(&out[3 * n4 + i0], b0); store_nt(&out[3 * n4 + i1], b1);
    } else {
        // Tail (never taken at the bench shape: n4 divisible by BLOCK*IPT).
        for (int k = 0; k < IPT; ++k) {
            const int i = base + k * BLOCK;
            if (i >= n4) continue;
            float4 mem = mem0[i & chw4_mask];
            for (int t = 0; t < LIF_T; ++t) {
                float4 s = lif_step(mem, x[(size_t)t * n4 + i]);
                out[(size_t)t * n4 + i] = s;
            }
        }
    }
}

extern "C" void kernel_launch(void* const* d_in, const int* in_sizes, int n_in,
                              void* d_out, int out_size, void* d_ws, size_t ws_size,
                              hipStream_t stream) {
    const float* x    = (const float*)d_in[0];   // [T,B,C,H,W]
    const float* mem0 = (const float*)d_in[1];   // [1,C,H,W]
    float* out        = (float*)d_out;           // [T,B,C,H,W]

    const int T = LIF_T;
    const int total = in_sizes[0];        // T*B*C*H*W
    const int bchw  = total / T;          // per-timestep elements
    const int n4    = bchw / 4;           // float4 count per timestep
    const int chw4  = in_sizes[1] / 4;    // mem0 float4 count (power of 2)

    const int block = BLOCK;
    const int grid  = (n4 + block * IPT - 1) / (block * IPT);

    lif_kernel<<<grid, block, 0, stream>>>(
        (const float4*)x, (const float4*)mem0, (float4*)out,
        n4, chw4 - 1);
}

// Round 8
// 219.106 us; speedup vs baseline: 1.0138x; 1.0138x over previous
//
#include <hip/hip_runtime.h>
#include <stdint.h>

// LIF recurrence: mem = tau*mem + x[t]; spike = (mem > v_th); mem *= (1-spike)
// x [T,B,C,H,W] fp32, mem0 [1,C,H,W] fp32, out [T,B,C,H,W] fp32.
// T=4, B=64, C=128, H=W=32. n4 = 2^21 float4 per timestep.
//
// Ledger (kernel = harness - ~147us): R0 84 | R2 MLP-null 81 | R3 stream-null
// 81 | R4 asm sc1-STORES FAIL (banned) | R5 nt-loads WIN 75 | R6 nt-stores
// WIN 72.5 | R7 occupancy-null 75.
// Model: the 512MiB pre-kernel fill leaves IF$ fully dirty-zero; our
// allocations force concurrent zero-writebacks -> HBM is saturated (~5-6
// TB/s real) though TCC counters only show our 192MiB. Only allocation-
// policy levers ever moved the number (+12%) — consistent.
// R8: device-scope nt LOADS (`sc1 nt`, read-only = correctness-safe) to
// take x out of L2 entirely (zero reuse there): stops read-allocate churn
// against the write stream. Hand-managed vmcnt: loads issue BEFORE the
// plane's stores; `s_waitcnt vmcnt(4)` with loaded regs tied through the
// asm (loads oldest -> done; 4 younger stores remain in flight) — exact
// R6 pipeline shape. If null or FETCH rises (lost IF$ hits): R6 is the
// ceiling -> ROOFLINE.

#ifndef LIF_T
#define LIF_T 4
#endif

#define BLOCK 256
#define IPT 4   // block-contiguous float4 per thread: 16KB/block per t-plane

typedef float vfloat4 __attribute__((ext_vector_type(4)));

// Device-scope non-temporal 16B load. Issue-only: NO waitcnt here — the
// matching WAIT4/WAIT0 macro below orders consumers via tied operands.
#define LOAD_NT_SC(dst, ptr)                                            \
    asm volatile("global_load_dwordx4 %0, %1, off sc1 nt"               \
                 : "=v"(dst) : "v"(ptr) : "memory")

// Wait until at most 4 vmem ops outstanding: our 4 loads (oldest) are done,
// the 4 younger nt-stores stay in flight. Tied "+v" operands force every
// consumer of r0..r3 to be scheduled after this wait (rule-#18 fix).
#define WAIT4(r0, r1, r2, r3)                                           \
    asm volatile("s_waitcnt vmcnt(4)"                                   \
                 : "+v"(r0), "+v"(r1), "+v"(r2), "+v"(r3) :: "memory")

#define WAIT0(r0, r1, r2, r3)                                           \
    asm volatile("s_waitcnt vmcnt(0)"                                   \
                 : "+v"(r0), "+v"(r1), "+v"(r2), "+v"(r3) :: "memory")

__device__ __forceinline__ void store_nt(float4* p, vfloat4 d) {
    __builtin_nontemporal_store(d, (vfloat4*)p);
}

__device__ __forceinline__ vfloat4 lif_step(float4& mem, const vfloat4 xt) {
    const float TAU = 0.25f;
    const float V_TH = 1.0f;
    vfloat4 s;
    mem.x = TAU * mem.x + xt.x;
    mem.y = TAU * mem.y + xt.y;
    mem.z = TAU * mem.z + xt.z;
    mem.w = TAU * mem.w + xt.w;
    s.x = (mem.x > V_TH) ? 1.0f : 0.0f;
    s.y = (mem.y > V_TH) ? 1.0f : 0.0f;
    s.z = (mem.z > V_TH) ? 1.0f : 0.0f;
    s.w = (mem.w > V_TH) ? 1.0f : 0.0f;
    mem.x = (mem.x > V_TH) ? 0.0f : mem.x;
    mem.y = (mem.y > V_TH) ? 0.0f : mem.y;
    mem.z = (mem.z > V_TH) ? 0.0f : mem.z;
    mem.w = (mem.w > V_TH) ? 0.0f : mem.w;
    return s;
}

__global__ __launch_bounds__(BLOCK) void
lif_kernel(const float4* __restrict__ x,     // [T, N4] float4 view
           const float4* __restrict__ mem0,  // [CHW4] float4 view (broadcast over B)
           float4* __restrict__ out,         // [T, N4]
           int n4, int chw4_mask) {
    const int base = blockIdx.x * (BLOCK * IPT) + threadIdx.x;
    const int i0 = base;
    const int i1 = base + BLOCK;
    const int i2 = base + 2 * BLOCK;
    const int i3 = base + 3 * BLOCK;

    if (i3 < n4) {
        float4 m0 = mem0[i0 & chw4_mask];
        float4 m1 = mem0[i1 & chw4_mask];
        float4 m2 = mem0[i2 & chw4_mask];
        float4 m3 = mem0[i3 & chw4_mask];

        vfloat4 a0, a1, a2, a3, b0, b1, b2, b3;

        // ---- prologue: t=0 loads, full drain (mem0 also resolves) ----
        LOAD_NT_SC(a0, &x[i0]); LOAD_NT_SC(a1, &x[i1]);
        LOAD_NT_SC(a2, &x[i2]); LOAD_NT_SC(a3, &x[i3]);
        WAIT0(a0, a1, a2, a3);

        // ---- t=0: compute a -> issue t=1 loads -> stores -> wait(4) ----
        a0 = lif_step(m0, a0); a1 = lif_step(m1, a1);
        a2 = lif_step(m2, a2); a3 = lif_step(m3, a3);
        LOAD_NT_SC(b0, &x[n4 + i0]); LOAD_NT_SC(b1, &x[n4 + i1]);
        LOAD_NT_SC(b2, &x[n4 + i2]); LOAD_NT_SC(b3, &x[n4 + i3]);
        store_nt(&out[i0], a0); store_nt(&out[i1], a1);
        store_nt(&out[i2], a2); store_nt(&out[i3], a3);
        WAIT4(b0, b1, b2, b3);

        // ---- t=1 ----
        b0 = lif_step(m0, b0); b1 = lif_step(m1, b1);
        b2 = lif_step(m2, b2); b3 = lif_step(m3, b3);
        LOAD_NT_SC(a0, &x[2 * n4 + i0]); LOAD_NT_SC(a1, &x[2 * n4 + i1]);
        LOAD_NT_SC(a2, &x[2 * n4 + i2]); LOAD_NT_SC(a3, &x[2 * n4 + i3]);
        store_nt(&out[n4 + i0], b0); store_nt(&out[n4 + i1], b1);
        store_nt(&out[n4 + i2], b2); store_nt(&out[n4 + i3], b3);
        WAIT4(a0, a1, a2, a3);

        // ---- t=2 ----
        a0 = lif_step(m0, a0); a1 = lif_step(m1, a1);
        a2 = lif_step(m2, a2); a3 = lif_step(m3, a3);
        LOAD_NT_SC(b0, &x[3 * n4 + i0]); LOAD_NT_SC(b1, &x[3 * n4 + i1]);
        LOAD_NT_SC(b2, &x[3 * n4 + i2]); LOAD_NT_SC(b3, &x[3 * n4 + i3]);
        store_nt(&out[2 * n4 + i0], a0); store_nt(&out[2 * n4 + i1], a1);
        store_nt(&out[2 * n4 + i2], a2); store_nt(&out[2 * n4 + i3], a3);
        WAIT4(b0, b1, b2, b3);

        // ---- t=3 ----
        b0 = lif_step(m0, b0); b1 = lif_step(m1, b1);
        b2 = lif_step(m2, b2); b3 = lif_step(m3, b3);
        store_nt(&out[3 * n4 + i0], b0); store_nt(&out[3 * n4 + i1], b1);
        store_nt(&out[3 * n4 + i2], b2); store_nt(&out[3 * n4 + i3], b3);
    } else {
        // Tail (never taken at the bench shape: n4 divisible by BLOCK*IPT).
        for (int k = 0; k < IPT; ++k) {
            const int i = base + k * BLOCK;
            if (i >= n4) continue;
            float4 mem = mem0[i & chw4_mask];
            for (int t = 0; t < LIF_T; ++t) {
                float4 xt4 = x[(size_t)t * n4 + i];
                vfloat4 xt = {xt4.x, xt4.y, xt4.z, xt4.w};
                vfloat4 s = lif_step(mem, xt);
                out[(size_t)t * n4 + i] =
                    make_float4(s.x, s.y, s.z, s.w);
            }
        }
    }
}

extern "C" void kernel_launch(void* const* d_in, const int* in_sizes, int n_in,
                              void* d_out, int out_size, void* d_ws, size_t ws_size,
                              hipStream_t stream) {
    const float* x    = (const float*)d_in[0];   // [T,B,C,H,W]
    const float* mem0 = (const float*)d_in[1];   // [1,C,H,W]
    float* out        = (float*)d_out;           // [T,B,C,H,W]

    const int T = LIF_T;
    const int total = in_sizes[0];        // T*B*C*H*W
    const int bchw  = total / T;          // per-timestep elements
    const int n4    = bchw / 4;           // float4 count per timestep
    const int chw4  = in_sizes[1] / 4;    // mem0 float4 count (power of 2)

    const int block = BLOCK;
    const int grid  = (n4 + block * IPT - 1) / (block * IPT);

    lif_kernel<<<grid, block, 0, stream>>>(
        (const float4*)x, (const float4*)mem0, (float4*)out,
        n4, chw4 - 1);
}